// Round 1
// baseline (295.486 us; speedup 1.0000x reference)
//
#include <hip/hip_runtime.h>
#include <math.h>

constexpr int B_   = 8;
constexpr int C_   = 64;
constexpr int H_   = 256;
constexpr int W_   = 256;
constexpr int CR_  = 128;
constexpr int HIN_ = 128;
constexpr int WIN_ = 128;

// align_corners=True 2x upsample: pos = j * (HIN-1)/(H-1) = j * 127/255
__device__ __forceinline__ float kScale() { return 127.0f / 255.0f; }

// ---------------------------------------------------------------------------
// Stage 1: scores[b, cr] = mean over (H, W) of the bilinearly-upsampled
// readout channel. Upsampling is linear & separable, so the mean equals a
// weighted sum of the ORIGINAL 128x128 slab with per-index column weights
// cw[i] = (1/256) * sum_j A[j,i].
// One block per (b, cr); 128 threads.
// ---------------------------------------------------------------------------
__global__ __launch_bounds__(128) void scores_kernel(
    const float* __restrict__ readout, float* __restrict__ scores)
{
    __shared__ float cw[HIN_];
    __shared__ float red[128];
    const int t  = threadIdx.x;       // 0..127
    const int bc = blockIdx.x;        // b*CR + cr

    // column weight for input index t
    float acc = 0.0f;
    const float s = kScale();
    for (int j = 0; j < H_; ++j) {
        float pos = j * s;
        int i0 = (int)floorf(pos);
        if (i0 > HIN_ - 2) i0 = HIN_ - 2;
        float w = pos - (float)i0;
        if (i0 == t)     acc += (1.0f - w);
        if (i0 + 1 == t) acc += w;
    }
    cw[t] = acc * (1.0f / 256.0f);
    __syncthreads();

    // weighted row sum for row t, then weighted column reduce
    const float* row = readout + ((size_t)bc * HIN_ + t) * WIN_;
    float rs = 0.0f;
    for (int l = 0; l < WIN_; ++l) rs += cw[l] * row[l];
    red[t] = cw[t] * rs;
    __syncthreads();
    for (int off = 64; off > 0; off >>= 1) {
        if (t < off) red[t] += red[t + off];
        __syncthreads();
    }
    if (t == 0) scores[bc] = red[0];
}

// ---------------------------------------------------------------------------
// Stage 2: top-C indices per batch, descending score, stable (lowest index
// wins ties) — matches jax.lax.top_k. One block per batch, CR threads.
// ---------------------------------------------------------------------------
__global__ __launch_bounds__(CR_) void topk_kernel(
    const float* __restrict__ scores, int* __restrict__ idx)
{
    __shared__ float s[CR_];
    const int t = threadIdx.x;
    const int b = blockIdx.x;
    s[t] = scores[b * CR_ + t];
    __syncthreads();
    const float mine = s[t];
    int rank = 0;
    for (int o = 0; o < CR_; ++o) {
        float so = s[o];
        rank += (so > mine) || (so == mine && o < t);
    }
    if (rank < C_) idx[b * C_ + rank] = t;
}

// ---------------------------------------------------------------------------
// Stage 3: fused upsample-on-the-fly + sigmoid-gated blend.
// Block = 256 threads covering 4 rows x 64 float4 lanes of one (b, c).
// Grid = B*C*(H/4).
// ---------------------------------------------------------------------------
__global__ __launch_bounds__(256) void fuse_kernel(
    const float* __restrict__ x, const float* __restrict__ readout,
    const float* __restrict__ weight, const float* __restrict__ bias,
    const int* __restrict__ idx, float* __restrict__ out)
{
    const int gid = blockIdx.x;
    const int bc  = gid / (H_ / 4);        // b*C + c
    const int h4  = gid % (H_ / 4);
    const int tid = threadIdx.x;
    const int row_in_blk = tid >> 6;       // 0..3
    const int lane       = tid & 63;       // float4 index along W
    const int h = h4 * 4 + row_in_blk;
    const int b = bc / C_;
    const int c = bc % C_;

    const int rc    = idx[b * C_ + c];
    const float w0  = weight[c * 2 + 0];
    const float w1  = weight[c * 2 + 1];
    const float bsv = bias[c];

    const float s = kScale();
    // vertical sample for this output row
    float hpos = h * s;
    int i0 = (int)floorf(hpos);
    if (i0 > HIN_ - 2) i0 = HIN_ - 2;
    const float wy = hpos - (float)i0;

    const float* r0 = readout + (((size_t)b * CR_ + rc) * HIN_ + i0) * WIN_;
    const float* r1 = r0 + WIN_;

    const float4* xin  = (const float4*)(x   + (((size_t)bc) * H_ + h) * W_);
    float4*       oo   = (float4*)      (out + (((size_t)bc) * H_ + h) * W_);

    const float4 xv = xin[lane];
    const float xf[4] = {xv.x, xv.y, xv.z, xv.w};
    float rv[4];
    const int wbase = lane * 4;
#pragma unroll
    for (int k = 0; k < 4; ++k) {
        float wpos = (wbase + k) * s;
        int j0 = (int)floorf(wpos);
        if (j0 > WIN_ - 2) j0 = WIN_ - 2;
        float wx = wpos - (float)j0;
        float top = r0[j0] + wx * (r0[j0 + 1] - r0[j0]);
        float bot = r1[j0] + wx * (r1[j0 + 1] - r1[j0]);
        rv[k] = top + wy * (bot - top);
    }

    float ov[4];
#pragma unroll
    for (int k = 0; k < 4; ++k) {
        float z = xf[k] * w0 + rv[k] * w1 + bsv;
        float g = 1.0f / (1.0f + __expf(-z));
        ov[k] = xf[k] + g * (rv[k] - xf[k]);
    }
    oo[lane] = make_float4(ov[0], ov[1], ov[2], ov[3]);
}

// ---------------------------------------------------------------------------
extern "C" void kernel_launch(void* const* d_in, const int* in_sizes, int n_in,
                              void* d_out, int out_size, void* d_ws, size_t ws_size,
                              hipStream_t stream)
{
    const float* x       = (const float*)d_in[0];   // [B, C, H, W]
    const float* readout = (const float*)d_in[1];   // [B, CR, HIN, WIN]
    const float* weight  = (const float*)d_in[2];   // [C, 2, 1, 1]
    const float* bias    = (const float*)d_in[3];   // [C]
    float* out = (float*)d_out;                     // [B, C, H, W]

    float* scores = (float*)d_ws;                               // B*CR floats
    int*   idx    = (int*)((char*)d_ws + B_ * CR_ * sizeof(float)); // B*C ints

    scores_kernel<<<B_ * CR_, 128, 0, stream>>>(readout, scores);
    topk_kernel<<<B_, CR_, 0, stream>>>(scores, idx);
    fuse_kernel<<<B_ * C_ * (H_ / 4), 256, 0, stream>>>(x, readout, weight, bias, idx, out);
}